// Round 7
// baseline (179.688 us; speedup 1.0000x reference)
//
#include <hip/hip_runtime.h>
#include <hip/hip_fp16.h>

// Volume: [B=2, X=128, Y=128, Z=128, C=1] fp32, grid: [B=2, N=2^21, 3] in [0,1].
// Output: [B, N, 1] fp32. source image flat idx = b*2^21 + x*2^14 + y*2^7 + z.
//
// R1 naive fp32 gathers               180 us (FETCH 594 MB)
// R2 fp16 volume (L2-resident)        132 us (FETCH 127 MB)
// R3 z-pair 8B windows, 4 req/sample   91 us (FETCH 112 MB)
// R4 bin+LDS-tile pipeline    FAILED  148 us (scatter write-amp)
// R5 16 loads in flight       NEUTRAL  91 us (MLP-invariant)
// R6 sc0 L1-bypass            NEUTRAL  92 us (not L1 allocate-bound)
//    => wall: ~3.3 cy per divergent line-request, invariant to MLP/occ/L1.
// R7 tiled volume: 64B line = 4(y) x 8(z) fp16 tile, y-fastest.
//    half offset = tile(x,yb,zb)*32 + zi*4 + yi.
//    Per x-plane the 2x2 (y,z) patch is 1 line unless tile-crossed
//    (P_y=1/4, P_z=1/8): expected 3.25 per-lane requests and 2.81 distinct
//    lines per sample (vs 4). Both surviving cost models predict -19..-30%.

#define TOTAL   (2 * 2097152)   // B * N samples
#define LOG2N   21
#define VOL     (128 * 128 * 128)
#define NVOX    (2 * VOL)
#define SPB     4               // samples per thread

typedef unsigned long long u64;
typedef unsigned int       u32;

// ---- pre-pass: fp32 volume -> tiled fp16 volume in workspace -------------
// One thread per 64B tile: (b, x, yb, zb), zb fastest (coalesced 64B store).
__global__ __launch_bounds__(256)
void ImageWarped_repack_kernel(const float* __restrict__ in,
                               __half* __restrict__ out)
{
    const int t  = blockIdx.x * 256 + threadIdx.x;   // 131072 threads
    const int zb = t & 15;
    const int yb = (t >> 4) & 31;
    const int x  = (t >> 9) & 127;
    const int b  = t >> 16;

    const float* src = in + ((size_t)b << 21) + (x << 14)
                          + ((yb << 2) << 7) + (zb << 3);

    unsigned short h[32];                 // h[zi*4 + yi]
    #pragma unroll
    for (int yi = 0; yi < 4; ++yi) {
        const float4 lo = *(const float4*)(src + (yi << 7));      // z 0..3
        const float4 hi = *(const float4*)(src + (yi << 7) + 4);  // z 4..7
        h[ 0 + yi] = __half_as_ushort(__float2half_rn(lo.x));
        h[ 4 + yi] = __half_as_ushort(__float2half_rn(lo.y));
        h[ 8 + yi] = __half_as_ushort(__float2half_rn(lo.z));
        h[12 + yi] = __half_as_ushort(__float2half_rn(lo.w));
        h[16 + yi] = __half_as_ushort(__float2half_rn(hi.x));
        h[20 + yi] = __half_as_ushort(__float2half_rn(hi.y));
        h[24 + yi] = __half_as_ushort(__float2half_rn(hi.z));
        h[28 + yi] = __half_as_ushort(__float2half_rn(hi.w));
    }

    u32 w[16];
    #pragma unroll
    for (int j = 0; j < 16; ++j)
        w[j] = (u32)h[2 * j] | ((u32)h[2 * j + 1] << 16);

    uint4* dst = (uint4*)(out + (size_t)t * 32);
    dst[0] = make_uint4(w[0],  w[1],  w[2],  w[3]);
    dst[1] = make_uint4(w[4],  w[5],  w[6],  w[7]);
    dst[2] = make_uint4(w[8],  w[9],  w[10], w[11]);
    dst[3] = make_uint4(w[12], w[13], w[14], w[15]);
}

__device__ __forceinline__ float col_get(u64 c, int yi)
{
    return __half2float(__ushort_as_half((unsigned short)(c >> (yi << 4))));
}

// Fetch + (z,y)-bilinear for one x-plane from the tiled volume.
__device__ __forceinline__ float plane_sample(const __half* __restrict__ imgt,
                                              int x,
                                              int yb1, int yi1, int yb2, int yi2,
                                              int zb1, int zi1, int zb2, int zi2,
                                              float wz, float wz2,
                                              float wy, float wy2)
{
    const int tb = (x << 5) | yb1;          // tile row for yb1
    const __half* p1 = imgt + (size_t)(((tb << 4) | zb1) << 5);

    u64 colz1, colz2;
    if (zb1 == zb2) {
        // One 16B load covers columns zi1 and zi1+1 (zi2 is zi1 or zi1+1).
        // 8B-aligned; may overread 8B into the next tile (never used; buffer
        // padded by 64B in kernel_launch's ws guard).
        const uint4 q = *(const uint4*)(p1 + (zi1 << 2));
        colz1 = ((u64)q.y << 32) | q.x;
        colz2 = (zi2 == zi1) ? colz1 : (((u64)q.w << 32) | q.z);
    } else {
        colz1 = *(const u64*)(p1 + (zi1 << 2));
        const __half* p2 = imgt + (size_t)(((tb << 4) | zb2) << 5);
        colz2 = *(const u64*)(p2 + (zi2 << 2));
    }

    const float vy1z1 = col_get(colz1, yi1);
    const float vy1z2 = col_get(colz2, yi1);

    float vy2z1, vy2z2;
    if (yb2 == yb1) {
        vy2z1 = col_get(colz1, yi2);
        vy2z2 = col_get(colz2, yi2);
    } else {
        // y-crossed (yi1==3): neighbor y-tile, same z columns. When z is
        // uncrossed these two loads hit the same line (2nd is an L1 hit).
        const int tc = (x << 5) | yb2;
        const u64 b1 = *(const u64*)(imgt + (size_t)(((tc << 4) | zb1) << 5) + (zi1 << 2));
        const u64 b2 = *(const u64*)(imgt + (size_t)(((tc << 4) | zb2) << 5) + (zi2 << 2));
        vy2z1 = col_get(b1, yi2);
        vy2z2 = col_get(b2, yi2);
    }

    // Literal two-weight lerps (integral coord -> both weights 0 preserved).
    return (vy1z1 * wz2 + vy1z2 * wz) * wy2
         + (vy2z1 * wz2 + vy2z2 * wz) * wy;
}

// ---- main: 4 samples/thread from the tiled fp16 volume -------------------
__global__ __launch_bounds__(256)
void ImageWarped_trilinear_t_kernel(const __half* __restrict__ imgt,
                                    const float* __restrict__ grid,
                                    float* __restrict__ out)
{
    // Batch-parity swizzle: round-robin blockIdx%8 -> XCD keeps one batch's
    // 4.19 MiB tiled volume per XCD L2.
    const int batch = blockIdx.x & 1;
    const int t     = (blockIdx.x >> 1) * 256 + threadIdx.x;
    const int i0    = (batch << LOG2N) | (t << 2);   // 4 consecutive samples

    const float4* __restrict__ G4 = (const float4*)grid;
    const int fb = (3 * i0) >> 2;
    const float4 ga = G4[fb + 0];
    const float4 gb = G4[fb + 1];
    const float4 gc = G4[fb + 2];

    const float cxs[SPB] = { ga.x, ga.w, gb.z, gc.y };
    const float cys[SPB] = { ga.y, gb.x, gb.w, gc.z };
    const float czs[SPB] = { ga.z, gb.y, gc.x, gc.w };

    const __half* __restrict__ img = imgt + ((size_t)batch << LOG2N);

    float res[SPB];
    #pragma unroll
    for (int k = 0; k < SPB; ++k) {
        const float xf = fminf(fmaxf(cxs[k] * 128.0f, 0.001f), 126.999f);
        const float yf = fminf(fmaxf(cys[k] * 128.0f, 0.001f), 126.999f);
        const float zf = fminf(fmaxf(czs[k] * 128.0f, 0.001f), 126.999f);

        const float x1f = floorf(xf), x2f = ceilf(xf);
        const float y1f = floorf(yf), y2f = ceilf(yf);
        const float z1f = floorf(zf), z2f = ceilf(zf);

        const float wx = xf - x1f, wx2 = x2f - xf;
        const float wy = yf - y1f, wy2 = y2f - yf;
        const float wz = zf - z1f, wz2 = z2f - zf;

        const int ix1 = (int)x1f, ix2 = (int)x2f;
        const int iy1 = (int)y1f, iy2 = (int)y2f;
        const int iz1 = (int)z1f, iz2 = (int)z2f;

        const int yb1 = iy1 >> 2, yi1 = iy1 & 3;
        const int yb2 = iy2 >> 2, yi2 = iy2 & 3;
        const int zb1 = iz1 >> 3, zi1 = iz1 & 7;
        const int zb2 = iz2 >> 3, zi2 = iz2 & 7;

        const float r1 = plane_sample(img, ix1, yb1, yi1, yb2, yi2,
                                      zb1, zi1, zb2, zi2, wz, wz2, wy, wy2);
        const float r2 = plane_sample(img, ix2, yb1, yi1, yb2, yi2,
                                      zb1, zi1, zb2, zi2, wz, wz2, wy, wy2);

        res[k] = r2 * wx + r1 * wx2;      // literal x-lerp
    }

    float4 o; o.x = res[0]; o.y = res[1]; o.z = res[2]; o.w = res[3];
    ((float4*)out)[i0 >> 2] = o;
}

// ---- fallback: direct fp32 gathers (if ws too small) ---------------------
__global__ __launch_bounds__(256)
void ImageWarped_trilinear_f_kernel(const float* __restrict__ image,
                                    const float* __restrict__ grid,
                                    float* __restrict__ out)
{
    const int i = blockIdx.x * 256 + threadIdx.x;
    if (i >= TOTAL) return;
    const float gx = grid[3 * i + 0];
    const float gy = grid[3 * i + 1];
    const float gz = grid[3 * i + 2];
    const float* __restrict__ img = image + ((size_t)(i >> LOG2N) << LOG2N);

    const float xf = fminf(fmaxf(gx * 128.0f, 0.001f), 126.999f);
    const float yf = fminf(fmaxf(gy * 128.0f, 0.001f), 126.999f);
    const float zf = fminf(fmaxf(gz * 128.0f, 0.001f), 126.999f);

    const float x1f = floorf(xf), x2f = ceilf(xf);
    const float y1f = floorf(yf), y2f = ceilf(yf);
    const float z1f = floorf(zf), z2f = ceilf(zf);
    const float wx = xf - x1f, wx2 = x2f - xf;
    const float wy = yf - y1f, wy2 = y2f - yf;
    const float wz = zf - z1f, wz2 = z2f - zf;

    const int bx1 = ((int)x1f) << 14, bx2 = ((int)x2f) << 14;
    const int by1 = ((int)y1f) << 7,  by2 = ((int)y2f) << 7;
    const int iz1 = (int)z1f,         iz2 = (int)z2f;

    const float c111 = img[bx1 + by1 + iz1], c211 = img[bx2 + by1 + iz1];
    const float c121 = img[bx1 + by2 + iz1], c221 = img[bx2 + by2 + iz1];
    const float c112 = img[bx1 + by1 + iz2], c212 = img[bx2 + by1 + iz2];
    const float c122 = img[bx1 + by2 + iz2], c222 = img[bx2 + by2 + iz2];

    const float l1 = (c211 * wx + c111 * wx2) * wy2 + (c221 * wx + c121 * wx2) * wy;
    const float l2 = (c212 * wx + c112 * wx2) * wy2 + (c222 * wx + c122 * wx2) * wy;
    out[i] = l2 * wz + l1 * wz2;
}

extern "C" void kernel_launch(void* const* d_in, const int* in_sizes, int n_in,
                              void* d_out, int out_size, void* d_ws, size_t ws_size,
                              hipStream_t stream)
{
    const float* image = (const float*)d_in[0];  // [2,128,128,128,1] fp32
    const float* grid  = (const float*)d_in[1];  // [2,2097152,3]     fp32
    float* out = (float*)d_out;                  // [2,2097152,1]     fp32

    // tiled fp16 volume + 64B pad (dwordx4 z-window may overread 8B)
    if (ws_size >= (size_t)NVOX * sizeof(__half) + 64) {
        __half* imgt = (__half*)d_ws;
        // 131072 tiles / 256 = 512 blocks
        ImageWarped_repack_kernel<<<512, 256, 0, stream>>>(image, imgt);
        ImageWarped_trilinear_t_kernel<<<TOTAL / (256 * SPB), 256, 0, stream>>>(
            imgt, grid, out);
    } else {
        ImageWarped_trilinear_f_kernel<<<TOTAL / 256, 256, 0, stream>>>(image, grid, out);
    }
}

// Round 8
// 174.973 us; speedup vs baseline: 1.0269x; 1.0269x over previous
//
#include <hip/hip_runtime.h>
#include <hip/hip_fp16.h>

// Volume: [B=2, X=128, Y=128, Z=128, C=1] fp32, grid: [B=2, N=2^21, 3] in [0,1].
// Output: [B, N, 1] fp32. image flat idx = b*2^21 + x*2^14 + y*2^7 + z.
//
// R1 naive fp32 gathers               180 us (FETCH 594 MB)
// R2 fp16 volume (L2-resident)        132 us (FETCH 127 MB)
// R3 z-pair 8B windows, 4 req/sample   91 us (FETCH 112 MB)
// R4 bin+LDS-tile pipeline    FAILED  148 us (scatter write-amp)
// R5 16 loads in flight       NEUTRAL  91 us (MLP-invariant)
// R6 sc0 L1-bypass            NEUTRAL  92 us (not L1-allocate-bound)
// R7 4x8 tiled volume         WORSE    97 us (fewer lines, more divergent
//                                            instructions -> line count is
//                                            NOT the cost unit)
// R8 revert to R5 = measured optimum. Wall: ~3.3 cy per divergent
//    lane-request in TCP/TA, invariant to MLP/occupancy/L1-bypass/locality.
//    Structural floor: 4 separated line-groups per trilinear stencil in any
//    single-copy layout; merging y-rows needs >=2x footprint -> breaks the
//    4 MiB/XCD L2 residency worth 4x in fetch. This is the roofline for
//    this access pattern.

#define TOTAL   (2 * 2097152)   // B * N samples
#define LOG2N   21              // N = 2^21 per batch; VOL = 2^21 voxels
#define VOL     (128 * 128 * 128)
#define NVOX    (2 * VOL)
#define SPB     4               // samples per thread

// ---- pre-pass: fp32 volume -> fp16 volume in workspace -------------------
__global__ __launch_bounds__(256)
void ImageWarped_cvt_fp16_kernel(const float* __restrict__ in,
                                 __half* __restrict__ out)
{
    const int i = blockIdx.x * 256 + threadIdx.x;   // NVOX/4 threads
    const float4 v = ((const float4*)in)[i];
    union { __half2 h2[2]; uint2 u; } p;
    p.h2[0] = __floats2half2_rn(v.x, v.y);
    p.h2[1] = __floats2half2_rn(v.z, v.w);
    ((uint2*)out)[i] = p.u;
}

// ---- main: 4 samples/thread, 16 gathers in flight ------------------------
__global__ __launch_bounds__(256)
void ImageWarped_trilinear_h4_kernel(const __half* __restrict__ image,
                                     const float* __restrict__ grid,
                                     float* __restrict__ out)
{
    // Batch-parity swizzle: round-robin blockIdx%8 -> XCD keeps one batch's
    // 4.19 MiB fp16 volume per XCD L2.
    const int batch = blockIdx.x & 1;
    const int t     = (blockIdx.x >> 1) * 256 + threadIdx.x; // thread in batch
    const int i0    = (batch << LOG2N) | (t << 2);           // 4 consecutive samples

    // 12 coords for 4 samples = 3 aligned float4 loads.
    const float4* __restrict__ G4 = (const float4*)grid;
    const int fb = (3 * i0) >> 2;
    const float4 ga = G4[fb + 0];
    const float4 gb = G4[fb + 1];
    const float4 gc = G4[fb + 2];

    const float cx[SPB] = { ga.x, ga.w, gb.z, gc.y };
    const float cy[SPB] = { ga.y, gb.x, gb.w, gc.z };
    const float cz[SPB] = { ga.z, gb.y, gc.x, gc.w };

    const __half* __restrict__ img = image + ((size_t)batch << LOG2N);

    float wxa[SPB], wx2a[SPB], wya[SPB], wy2a[SPB], wza[SPB], wz2a[SPB];
    int   sha[SPB];
    uint2 w11[SPB], w21[SPB], w12[SPB], w22[SPB];

    // Phase 1: addresses + ALL 16 gathers issued before any use.
    #pragma unroll
    for (int k = 0; k < SPB; ++k) {
        const float xf = fminf(fmaxf(cx[k] * 128.0f, 0.001f), 126.999f);
        const float yf = fminf(fmaxf(cy[k] * 128.0f, 0.001f), 126.999f);
        const float zf = fminf(fmaxf(cz[k] * 128.0f, 0.001f), 126.999f);

        const float x1f = floorf(xf), x2f = ceilf(xf);
        const float y1f = floorf(yf), y2f = ceilf(yf);
        const float z1f = floorf(zf), z2f = ceilf(zf);

        // Literal reference weights (integral coord -> both weights 0).
        wxa[k] = xf - x1f;  wx2a[k] = x2f - xf;
        wya[k] = yf - y1f;  wy2a[k] = y2f - yf;
        wza[k] = zf - z1f;  wz2a[k] = z2f - zf;

        const int bx1 = ((int)x1f) << 14, bx2 = ((int)x2f) << 14;
        const int by1 = ((int)y1f) << 7,  by2 = ((int)y2f) << 7;
        const int iz1 = (int)z1f;

        // 4-half window [ze, ze+3]: contains z1,z1+1; 4B-aligned; in-bounds.
        const int ze = min(iz1 & ~1, 124);
        sha[k] = (iz1 - ze) << 4;               // 0/16/32-bit shift

        const __half* p = img + ze;
        w11[k] = *(const uint2*)(p + bx1 + by1);
        w21[k] = *(const uint2*)(p + bx2 + by1);
        w12[k] = *(const uint2*)(p + bx1 + by2);
        w22[k] = *(const uint2*)(p + bx2 + by2);
    }

    // Phase 2: extract z-pairs, lerp, pack float4 result.
    float res[SPB];
    #pragma unroll
    for (int k = 0; k < SPB; ++k) {
        auto zl = [&](uint2 u) -> float {
            unsigned long long w = ((unsigned long long)u.y << 32) | u.x;
            w >>= sha[k];
            union { unsigned int u32; __half2 h; } c;
            c.u32 = (unsigned int)w;            // (c_z1, c_z2)
            const float2 f = __half22float2(c.h);
            return f.x * wz2a[k] + f.y * wza[k];   // literal z-lerp
        };
        const float q11 = zl(w11[k]);
        const float q21 = zl(w21[k]);
        const float q12 = zl(w12[k]);
        const float q22 = zl(w22[k]);
        res[k] = (q21 * wxa[k] + q11 * wx2a[k]) * wy2a[k]
               + (q22 * wxa[k] + q12 * wx2a[k]) * wya[k];
    }

    float4 o; o.x = res[0]; o.y = res[1]; o.z = res[2]; o.w = res[3];
    ((float4*)out)[i0 >> 2] = o;                 // aligned 16B store
}

// ---- fallback: direct fp32 gathers (if ws too small) ---------------------
__global__ __launch_bounds__(256)
void ImageWarped_trilinear_f_kernel(const float* __restrict__ image,
                                    const float* __restrict__ grid,
                                    float* __restrict__ out)
{
    const int i = blockIdx.x * 256 + threadIdx.x;
    if (i >= TOTAL) return;
    const float gx = grid[3 * i + 0];
    const float gy = grid[3 * i + 1];
    const float gz = grid[3 * i + 2];
    const float* __restrict__ img = image + ((size_t)(i >> LOG2N) << LOG2N);

    const float xf = fminf(fmaxf(gx * 128.0f, 0.001f), 126.999f);
    const float yf = fminf(fmaxf(gy * 128.0f, 0.001f), 126.999f);
    const float zf = fminf(fmaxf(gz * 128.0f, 0.001f), 126.999f);

    const float x1f = floorf(xf), x2f = ceilf(xf);
    const float y1f = floorf(yf), y2f = ceilf(yf);
    const float z1f = floorf(zf), z2f = ceilf(zf);
    const float wx = xf - x1f, wx2 = x2f - xf;
    const float wy = yf - y1f, wy2 = y2f - yf;
    const float wz = zf - z1f, wz2 = z2f - zf;

    const int bx1 = ((int)x1f) << 14, bx2 = ((int)x2f) << 14;
    const int by1 = ((int)y1f) << 7,  by2 = ((int)y2f) << 7;
    const int iz1 = (int)z1f,         iz2 = (int)z2f;

    const float c111 = img[bx1 + by1 + iz1], c211 = img[bx2 + by1 + iz1];
    const float c121 = img[bx1 + by2 + iz1], c221 = img[bx2 + by2 + iz1];
    const float c112 = img[bx1 + by1 + iz2], c212 = img[bx2 + by1 + iz2];
    const float c122 = img[bx1 + by2 + iz2], c222 = img[bx2 + by2 + iz2];

    const float l1 = (c211 * wx + c111 * wx2) * wy2 + (c221 * wx + c121 * wx2) * wy;
    const float l2 = (c212 * wx + c112 * wx2) * wy2 + (c222 * wx + c122 * wx2) * wy;
    out[i] = l2 * wz + l1 * wz2;
}

extern "C" void kernel_launch(void* const* d_in, const int* in_sizes, int n_in,
                              void* d_out, int out_size, void* d_ws, size_t ws_size,
                              hipStream_t stream)
{
    const float* image = (const float*)d_in[0];  // [2,128,128,128,1] fp32
    const float* grid  = (const float*)d_in[1];  // [2,2097152,3]     fp32
    float* out = (float*)d_out;                  // [2,2097152,1]     fp32

    if (ws_size >= (size_t)NVOX * sizeof(__half)) {
        __half* img16 = (__half*)d_ws;
        ImageWarped_cvt_fp16_kernel<<<NVOX / 4 / 256, 256, 0, stream>>>(image, img16);
        ImageWarped_trilinear_h4_kernel<<<TOTAL / (256 * SPB), 256, 0, stream>>>(
            img16, grid, out);
    } else {
        ImageWarped_trilinear_f_kernel<<<TOTAL / 256, 256, 0, stream>>>(image, grid, out);
    }
}